// Round 18
// baseline (177.683 us; speedup 1.0000x reference)
//
#include <hip/hip_runtime.h>

#define N_NODES 100000
#define N_EDGES 3200000
#define IN_FEAT 512
#define HID 16
#define BNODES 128                        // nodes per bucket (dst >> 7)
#define NB 782                            // ceil(100000/128)
#define BCAP 6144                         // fixed bucket capacity (E=4092, sigma~64)
#define CHUNK2 2048
#define NCHUNK2 ((N_EDGES + CHUNK2 - 1) / CHUNK2)   // 1563
#define G1_ROWS 64
#define G1_GRID ((N_NODES + 1 + G1_ROWS - 1) / G1_ROWS)  // 1563 == NCHUNK2
#define FUSED_GRID (NCHUNK2 + G1_GRID)    // 3126

typedef float f32x4 __attribute__((ext_vector_type(4)));

__device__ __forceinline__ int load_dst(const void* ei, int is64, int e) {
    if (is64) return (int)((const long long*)ei)[(long long)N_EDGES + e];
    return ((const int*)ei)[N_EDGES + e];
}
__device__ __forceinline__ int load_src(const void* ei, int is64, int e) {
    if (is64) return (int)((const long long*)ei)[e];
    return ((const int*)ei)[e];
}

// ---- FUSED sort || gemm: even blocks sort a 2048-edge chunk, odd do gemm ---
// Independent phases share one launch so sort's LDS/barrier work overlaps
// gemm's HBM streaming. LDS union: gemm 33.8 KB, sort 24.6 KB.
__global__ __launch_bounds__(256, 8)
void k_sort_gemm(const void* ei, int* __restrict__ gcnt,
                 unsigned* __restrict__ colp,
                 const float* __restrict__ x, const float* __restrict__ W1,
                 float* __restrict__ xw) {
    __shared__ __attribute__((aligned(16))) char smem[33792];
    int tid = threadIdx.x;

    if ((blockIdx.x & 1) == 0) {
        // ---------------- sort path ----------------------------------------
        unsigned* sorted = (unsigned*)smem;            // 8192 B
        short*    bsh    = (short*)(smem + 8192);      // 4096 B
        int*      hist   = (int*)(smem + 12288);       // 4096 B
        int*      scanL  = (int*)(smem + 16384);       // 4096 B
        int*      gbase  = (int*)(smem + 20480);       // 4096 B
        int*      wsum   = (int*)(smem + 24576);       // 16 B
        int*      sflag  = (int*)(smem + 24592);       // 4 B
        int cidx = blockIdx.x >> 1;
        int base = cidx * CHUNK2;
        int chunkN = min(CHUNK2, N_EDGES - base);

        if (tid < 64) {                    // wave 0: probe storage width
            const int* p = (const int*)ei;
            bool nz = (p[2 * tid + 1] != 0);
            unsigned long long m = __ballot(nz);
            if (tid == 0) *sflag = (m == 0ull) ? 1 : 0;   // 1 => int64
        }
        for (int i = tid; i < 1024; i += 256) hist[i] = 0;
        __syncthreads();
        int is64 = *sflag;

        unsigned ent[8];
        short bkt[8];
#pragma unroll
        for (int k = 0; k < 8; ++k) {
            int i = k * 256 + tid;
            if (i < chunkN) {
                int e = base + i;
                int s = load_src(ei, is64, e);
                int d = load_dst(ei, is64, e);
                int b = d >> 7;
                ent[k] = ((unsigned)s << 7) | (unsigned)(d & 127);
                bkt[k] = (short)b;
                atomicAdd(&hist[b], 1);
            } else bkt[k] = -1;
        }
        __syncthreads();

        // exclusive scan of hist[0..1023]: 4 slots/thread + shfl wave scan
        int h0 = hist[4 * tid], h1 = hist[4 * tid + 1];
        int h2 = hist[4 * tid + 2], h3 = hist[4 * tid + 3];
        int sl = h0 + h1 + h2 + h3;
        int lane = tid & 63, wv = tid >> 6;
        int incl = sl;
#pragma unroll
        for (int o = 1; o < 64; o <<= 1) {
            int up = __shfl_up(incl, o, 64);
            if (lane >= o) incl += up;
        }
        if (lane == 63) wsum[wv] = incl;
        __syncthreads();
        int wpre = 0;
        for (int q = 0; q < wv; ++q) wpre += wsum[q];
        int run = wpre + incl - sl;        // exclusive prefix for slot 4t
        scanL[4 * tid] = run;     run += h0;
        scanL[4 * tid + 1] = run; run += h1;
        scanL[4 * tid + 2] = run; run += h2;
        scanL[4 * tid + 3] = run;
        hist[4 * tid] = 0; hist[4 * tid + 1] = 0;
        hist[4 * tid + 2] = 0; hist[4 * tid + 3] = 0;
        __syncthreads();

#pragma unroll
        for (int k = 0; k < 8; ++k) {
            if (bkt[k] >= 0) {
                int b = bkt[k];
                int pos = atomicAdd(&hist[b], 1);
                int dst = scanL[b] + pos;
                sorted[dst] = ent[k];
                bsh[dst] = bkt[k];
            }
        }
        __syncthreads();

        for (int b = tid; b < NB; b += 256) {
            int cnt = scanL[b + 1] - scanL[b];
            gbase[b] = b * BCAP + ((cnt > 0) ? atomicAdd(&gcnt[b], cnt) : 0);
        }
        __syncthreads();

        for (int i = tid; i < chunkN; i += 256) {
            int b = bsh[i];
            colp[gbase[b] + (i - scanL[b])] = sorted[i];
        }
        return;
    }

    // ---------------- gemm path (verbatim R17) ------------------------------
    float* smemA = (float*)smem;           // [64][68] = 17408 B
    float* smemB = (float*)(smem + 17408); // [64][64] = 16384 B
    int l = tid & 63;
    int w = __builtin_amdgcn_readfirstlane(tid >> 6);
    int w64 = tid & ~63;
    size_t rowbase = (size_t)(blockIdx.x >> 1) * G1_ROWS;
    const float4* xg = (const float4*)x;
    float acc[16];
#pragma unroll
    for (int f = 0; f < 16; ++f) acc[f] = 0.f;

#define G1_DMA(DSTBASE, C)                                                    \
    {                                                                         \
        _Pragma("unroll")                                                     \
        for (int i = 0; i < 4; ++i) {                                         \
            int li = tid + i * 256;                                           \
            int r = li >> 4, kin = li & 15;                                   \
            int f4l = kin ^ (r & 15);                                         \
            size_t grow = rowbase + r;                                        \
            size_t g4 = (grow < (size_t)N_NODES)                              \
                        ? (grow * 128 + (C) * 16 + f4l)                       \
                        : (size_t)((C) * 16 + f4l);                           \
            const float4* srcp = xg + g4;                                     \
            float* dstf = (DSTBASE) + (size_t)(w64 + i * 256) * 4;            \
            __builtin_amdgcn_global_load_lds(                                 \
                (const __attribute__((address_space(1))) void*)srcp,          \
                (__attribute__((address_space(3))) void*)dstf, 16, 0, 0);     \
        }                                                                     \
    }

    G1_DMA(smemA, 0);
#pragma unroll 1
    for (int c = 0; c < 8; ++c) {
        asm volatile("s_waitcnt vmcnt(0)" ::: "memory");
        __syncthreads();
        float* cur = (c & 1) ? smemB : smemA;
        float* nxt = (c & 1) ? smemA : smemB;
        if (c < 7) G1_DMA(nxt, c + 1);
        const float* lbase = cur + l * 64;
#pragma unroll
        for (int kk = 0; kk < 4; ++kk) {
            int phys = (4 * w + kk) ^ (l & 15);
            f32x4 xv = *(const f32x4*)(lbase + phys * 4);
#pragma unroll
            for (int j = 0; j < 4; ++j) {
                const float* wr = W1 + (size_t)(c * 64 + 16 * w + 4 * kk + j) * HID;
#pragma unroll
                for (int f = 0; f < 16; ++f)
                    acc[f] = fmaf(xv[j], wr[f], acc[f]);
            }
        }
    }
#undef G1_DMA
    __syncthreads();

    float* red = smemA;
#pragma unroll
    for (int f = 0; f < 16; ++f)
        red[l * 68 + w * 16 + f] = acc[f];
    __syncthreads();
    int r = tid >> 2;
    int fg = (tid & 3) * 4;
    size_t node = rowbase + r;
    if (node <= (size_t)N_NODES) {
        float o0 = 0.f, o1 = 0.f, o2 = 0.f, o3 = 0.f;
#pragma unroll
        for (int qq = 0; qq < 4; ++qq) {
            const float* rr = &red[r * 68 + qq * 16 + fg];
            o0 += rr[0]; o1 += rr[1]; o2 += rr[2]; o3 += rr[3];
        }
        float4 out = (node < (size_t)N_NODES)
                     ? make_float4(o0, o1, o2, o3)
                     : make_float4(0.f, 0.f, 0.f, 0.f);
        *(float4*)(xw + node * HID + fg) = out;
    }
}

// ---- node-CSR build (one bucket per block) ---------------------------------
__global__ __launch_bounds__(256)
void k_csr(const int* __restrict__ gcnt, const unsigned* __restrict__ colp,
           int* __restrict__ noff, int* __restrict__ ndeg,
           float* __restrict__ dinv, int* __restrict__ colf) {
    __shared__ int hist[BNODES];
    __shared__ int bse[BNODES];
    __shared__ int sc[256];
    int b = blockIdx.x, tid = threadIdx.x;
    if (tid < BNODES) hist[tid] = 0;
    __syncthreads();
    int s0 = b * BCAP, s1 = s0 + gcnt[b];
    for (int i = s0 + tid; i < s1; i += 256)
        atomicAdd(&hist[colp[i] & 127u], 1);
    __syncthreads();
    int v = (tid < BNODES) ? hist[tid] : 0;
    sc[tid] = v;
    __syncthreads();
    for (int o = 1; o < 256; o <<= 1) {
        int t = (tid >= o) ? sc[tid - o] : 0;
        __syncthreads();
        sc[tid] += t;
        __syncthreads();
    }
    int excl = sc[tid] - v;
    if (tid < BNODES) {
        bse[tid] = s0 + excl;
        int node = (b << 7) + tid;
        if (node < N_NODES) {
            noff[node] = s0 + excl;
            ndeg[node] = v;
            dinv[node] = rsqrtf((float)v + 1.0f);   // +1 self-loop
        }
    }
    __syncthreads();
    if (tid < BNODES) hist[tid] = 0;
    __syncthreads();
    for (int i = s0 + tid; i < s1; i += 256) {
        unsigned e = colp[i];
        int ld = (int)(e & 127u);
        int pos = atomicAdd(&hist[ld], 1);
        colf[bse[ld] + pos] = (int)(e >> 7);
    }
}

// ---- layer-1 aggregation + fused layer-2: 16 lanes/node, NO atomics --------
__global__ __launch_bounds__(256)
void k_gather1(const int* __restrict__ noff, const int* __restrict__ ndeg,
               const int* __restrict__ colf, const float* __restrict__ dinv,
               const float* __restrict__ xw, const float* __restrict__ b1,
               const float* __restrict__ W2, float* __restrict__ h2s) {
    int t = blockIdx.x * 256 + threadIdx.x;   // grid exactly N_NODES*16
    int node = t >> 4;
    int l = t & 15;
    int start = noff[node];
    int end = start + ndeg[node];
    const f32x4* xw4 = (const f32x4*)xw;
    float acc[16];
#pragma unroll
    for (int r = 0; r < 16; ++r) acc[r] = 0.f;
    for (int j = start; j < end; j += 16) {
        int jl = j + l;
        int jj = min(jl, end - 1);
        int s = colf[jj];
        float ds = (jl < end) ? dinv[s] : 0.f;
        const f32x4* row = xw4 + (size_t)s * 4;
        f32x4 r0 = row[0], r1 = row[1], r2 = row[2], r3 = row[3];
        acc[0]  = fmaf(ds, r0.x, acc[0]);  acc[1]  = fmaf(ds, r0.y, acc[1]);
        acc[2]  = fmaf(ds, r0.z, acc[2]);  acc[3]  = fmaf(ds, r0.w, acc[3]);
        acc[4]  = fmaf(ds, r1.x, acc[4]);  acc[5]  = fmaf(ds, r1.y, acc[5]);
        acc[6]  = fmaf(ds, r1.z, acc[6]);  acc[7]  = fmaf(ds, r1.w, acc[7]);
        acc[8]  = fmaf(ds, r2.x, acc[8]);  acc[9]  = fmaf(ds, r2.y, acc[9]);
        acc[10] = fmaf(ds, r2.z, acc[10]); acc[11] = fmaf(ds, r2.w, acc[11]);
        acc[12] = fmaf(ds, r3.x, acc[12]); acc[13] = fmaf(ds, r3.y, acc[13]);
        acc[14] = fmaf(ds, r3.z, acc[14]); acc[15] = fmaf(ds, r3.w, acc[15]);
    }
    float c8[8];
#pragma unroll
    for (int k = 0; k < 8; ++k) {
        float a0 = acc[2 * k], a1 = acc[2 * k + 1];
        float o0 = __shfl_xor(a0, 1, 16);
        float o1 = __shfl_xor(a1, 1, 16);
        c8[k] = (l & 1) ? (a1 + o1) : (a0 + o0);
    }
    float c4[4];
#pragma unroll
    for (int k = 0; k < 4; ++k) {
        float a0 = c8[2 * k], a1 = c8[2 * k + 1];
        float o0 = __shfl_xor(a0, 2, 16);
        float o1 = __shfl_xor(a1, 2, 16);
        c4[k] = (l & 2) ? (a1 + o1) : (a0 + o0);
    }
    float c2[2];
#pragma unroll
    for (int k = 0; k < 2; ++k) {
        float a0 = c4[2 * k], a1 = c4[2 * k + 1];
        float o0 = __shfl_xor(a0, 4, 16);
        float o1 = __shfl_xor(a1, 4, 16);
        c2[k] = (l & 4) ? (a1 + o1) : (a0 + o0);
    }
    float a0 = c2[0], a1 = c2[1];
    float o0 = __shfl_xor(a0, 8, 16);
    float o1 = __shfl_xor(a1, 8, 16);
    float tot = (l & 8) ? (a1 + o1) : (a0 + o0);

    float dd = dinv[node];
    float selfr = xw[(size_t)node * HID + l];
    float vv = fmaf(dd, tot + dd * selfr, b1[l]);
    float h = fmaxf(vv, 0.f);

    float2 w2 = ((const float2*)W2)[l];
    float g0 = h * w2.x, g1 = h * w2.y;
#pragma unroll
    for (int d = 1; d < 16; d <<= 1) {
        g0 += __shfl_xor(g0, d, 16);
        g1 += __shfl_xor(g1, d, 16);
    }
    if (l == 0)
        ((float2*)h2s)[node] = make_float2(g0 * dd, g1 * dd);
    if (t == 0)
        ((float2*)h2s)[N_NODES] = make_float2(0.f, 0.f);   // sentinel
}

// ---- layer-2 aggregation + log_softmax: 16 lanes/node ----------------------
__global__ __launch_bounds__(256)
void k_gather2(const int* __restrict__ noff, const int* __restrict__ ndeg,
               const int* __restrict__ colf, const float* __restrict__ dinv,
               const float* __restrict__ h2s, const float* __restrict__ b2,
               float* __restrict__ y) {
    int t = blockIdx.x * 256 + threadIdx.x;
    int node = t >> 4;
    int l = t & 15;
    int start = noff[node];
    int end = start + ndeg[node];
    const float2* h2v = (const float2*)h2s;
    float g0 = 0.f, g1 = 0.f;
    for (int j = start; j < end; j += 16) {
        int jl = j + l;
        int jj = min(jl, end - 1);
        int s = colf[jj];
        s = (jl < end) ? s : N_NODES;
        float2 hv = h2v[s];
        g0 += hv.x; g1 += hv.y;
    }
#pragma unroll
    for (int d = 1; d < 16; d <<= 1) {
        g0 += __shfl_xor(g0, d, 16);
        g1 += __shfl_xor(g1, d, 16);
    }
    if (l == 0) {
        float2 self = h2v[node];
        float di = dinv[node];
        float v0 = fmaf(di, g0 + self.x, b2[0]);
        float v1 = fmaf(di, g1 + self.y, b2[1]);
        float m = fmaxf(v0, v1);
        float lse = m + logf(expf(v0 - m) + expf(v1 - m));
        ((float2*)y)[node] = make_float2(v0 - lse, v1 - lse);
    }
}

extern "C" void kernel_launch(void* const* d_in, const int* in_sizes, int n_in,
                              void* d_out, int out_size, void* d_ws, size_t ws_size,
                              hipStream_t stream) {
    const float* x  = (const float*)d_in[0];
    const void*  ei = d_in[1];
    const float* W1 = (const float*)d_in[2];
    const float* b1 = (const float*)d_in[3];
    const float* W2 = (const float*)d_in[4];
    const float* b2 = (const float*)d_in[5];
    float* y = (float*)d_out;

    char* w = (char*)d_ws;
    int*      gcnt = (int*)(w + 0);               // NB ints
    float*    dinv = (float*)(w + 4096);          // 400 KB
    int*      noff = (int*)(w + 413696);          // 400 KB
    int*      ndeg = (int*)(w + 823296);          // 400 KB
    unsigned* colp = (unsigned*)(w + 1232896);    // NB*BCAP*4 = 19.2 MB
    int*      colf = (int*)(w + 20451328);        // 19.2 MB
    float*    xw   = (float*)(w + 39669760);      // (N+1)*16 f32
    float*    h2s  = (float*)(w + 46069824);      // (N+1)*2 f32
    // total ws use: ~46.9 MB

    hipMemsetAsync(gcnt, 0, NB * sizeof(int), stream);
    k_sort_gemm<<<FUSED_GRID, 256, 0, stream>>>(ei, gcnt, colp, x, W1, xw);
    k_csr<<<NB, 256, 0, stream>>>(gcnt, colp, noff, ndeg, dinv, colf);
    k_gather1<<<(N_NODES * 16) / 256, 256, 0, stream>>>(noff, ndeg, colf, dinv,
                                                        xw, b1, W2, h2s);
    k_gather2<<<(N_NODES * 16) / 256, 256, 0, stream>>>(noff, ndeg, colf, dinv,
                                                        h2s, b2, y);
}

// Round 19
// 153.586 us; speedup vs baseline: 1.1569x; 1.1569x over previous
//
#include <hip/hip_runtime.h>

#define N_NODES 100000
#define N_EDGES 3200000
#define IN_FEAT 512
#define HID 16
#define BNODES 128                        // nodes per bucket (dst >> 7)
#define NB 782                            // ceil(100000/128)
#define BCAP 6144                         // fixed bucket capacity (E=4092, sigma~64)
#define CHUNK 8192
#define NCHUNKS ((N_EDGES + CHUNK - 1) / CHUNK)   // 391
#define G1_ROWS 64
#define G1_GRID ((N_NODES + 1 + G1_ROWS - 1) / G1_ROWS)  // 1563, covers sentinel

typedef float f32x4 __attribute__((ext_vector_type(4)));

__device__ __forceinline__ int load_dst(const void* ei, int is64, int e) {
    if (is64) return (int)((const long long*)ei)[(long long)N_EDGES + e];
    return ((const int*)ei)[N_EDGES + e];
}
__device__ __forceinline__ int load_src(const void* ei, int is64, int e) {
    if (is64) return (int)((const long long*)ei)[e];
    return ((const int*)ei)[e];
}

// ---- per-chunk LDS counting sort -> fixed-capacity buckets -----------------
// R17 structure; scan replaced by 2-barrier shfl scan (was 20 barriers).
__global__ __launch_bounds__(1024)
void k_sortscatter(const void* ei, int* __restrict__ gcnt,
                   unsigned* __restrict__ colp) {
    __shared__ unsigned sorted[CHUNK];     // 32 KB
    __shared__ short bsh[CHUNK];           // 16 KB
    __shared__ int hist[1024];
    __shared__ int scanL[1024 + 1];
    __shared__ int gbase[1024];
    __shared__ int wsum[16];
    __shared__ int sflag;
    int tid = threadIdx.x;
    int base = blockIdx.x * CHUNK;
    int chunkN = min(CHUNK, N_EDGES - base);

    if (tid < 64) {                        // wave 0: probe storage width
        const int* p = (const int*)ei;
        bool nz = (p[2 * tid + 1] != 0);
        unsigned long long m = __ballot(nz);
        if (tid == 0) sflag = (m == 0ull) ? 1 : 0;   // 1 => int64 storage
    }
    hist[tid] = 0;
    __syncthreads();
    int is64 = sflag;

    unsigned ent[8];
    short bkt[8];
#pragma unroll
    for (int k = 0; k < 8; ++k) {
        int i = k * 1024 + tid;
        if (i < chunkN) {
            int e = base + i;
            int s = load_src(ei, is64, e);
            int d = load_dst(ei, is64, e);
            int b = d >> 7;
            ent[k] = ((unsigned)s << 7) | (unsigned)(d & 127);
            bkt[k] = (short)b;
            atomicAdd(&hist[b], 1);
        } else bkt[k] = -1;
    }
    __syncthreads();

    // exclusive scan of hist[0..1023]: shfl wave scan + wave-sum prefix
    int v = hist[tid];
    int lane = tid & 63, wv = tid >> 6;
    int incl = v;
#pragma unroll
    for (int o = 1; o < 64; o <<= 1) {
        int up = __shfl_up(incl, o, 64);
        if (lane >= o) incl += up;
    }
    if (lane == 63) wsum[wv] = incl;
    __syncthreads();
    int wpre = 0;
#pragma unroll
    for (int q = 0; q < 16; ++q)
        wpre += (q < wv) ? wsum[q] : 0;
    scanL[tid] = wpre + incl - v;          // exclusive prefix
    if (tid == 1023) scanL[1024] = wpre + incl;
    hist[tid] = 0;                         // reuse as within-bucket cursor
    __syncthreads();

#pragma unroll
    for (int k = 0; k < 8; ++k) {
        if (bkt[k] >= 0) {
            int b = bkt[k];
            int pos = atomicAdd(&hist[b], 1);
            int dst = scanL[b] + pos;
            sorted[dst] = ent[k];
            bsh[dst] = bkt[k];
        }
    }
    __syncthreads();

    if (tid < NB) {
        int cnt = scanL[tid + 1] - scanL[tid];
        gbase[tid] = tid * BCAP + ((cnt > 0) ? atomicAdd(&gcnt[tid], cnt) : 0);
    }
    __syncthreads();

    for (int i = tid; i < chunkN; i += 1024) {
        int b = bsh[i];
        colp[gbase[b] + (i - scanL[b])] = sorted[i];
    }
}

// ---- FUSED: blocks [0,NB) build node-CSR; blocks [NB,NB+G1_GRID) do gemm ---
// gemm: xw = x @ W1 raw (dinv applied at gather). Staging via
// global_load_lds dwordx4 (async DMA, linear LDS dest, pre-swizzled source
// f4 ^= row&15 for conflict-free reads), double-buffered: chunk c+1's DMA
// issued BEFORE chunk c's compute; one vmcnt(0)+barrier per chunk.
__global__ __launch_bounds__(256, 8)
void k_csr_gemm(const int* __restrict__ gcnt, const unsigned* __restrict__ colp,
                const float* __restrict__ x, const float* __restrict__ W1,
                int* __restrict__ noff, int* __restrict__ ndeg,
                float* __restrict__ dinv, int* __restrict__ colf,
                float* __restrict__ xw) {
    __shared__ float smemA[G1_ROWS * 68];  // 17.4 KB: buf0 (16KB) + combine
    __shared__ float smemB[G1_ROWS * 64];  // 16 KB: buf1
    int tid = threadIdx.x;

    if (blockIdx.x < NB) {
        // ---------------- node-CSR build (one bucket per block) -------------
        int* hist = (int*)smemA;           // [128]
        int* bse  = hist + BNODES;         // [128]
        int* sc   = bse + BNODES;          // [256]
        int b = blockIdx.x;
        if (tid < BNODES) hist[tid] = 0;
        __syncthreads();
        int s0 = b * BCAP, s1 = s0 + gcnt[b];
        for (int i = s0 + tid; i < s1; i += 256)
            atomicAdd(&hist[colp[i] & 127u], 1);
        __syncthreads();
        int v = (tid < BNODES) ? hist[tid] : 0;
        sc[tid] = v;
        __syncthreads();
        for (int o = 1; o < 256; o <<= 1) {
            int t = (tid >= o) ? sc[tid - o] : 0;
            __syncthreads();
            sc[tid] += t;
            __syncthreads();
        }
        int excl = sc[tid] - v;
        if (tid < BNODES) {
            bse[tid] = s0 + excl;
            int node = (b << 7) + tid;
            if (node < N_NODES) {
                noff[node] = s0 + excl;
                ndeg[node] = v;
                dinv[node] = rsqrtf((float)v + 1.0f);   // +1 self-loop
            }
        }
        __syncthreads();
        if (tid < BNODES) hist[tid] = 0;
        __syncthreads();
        for (int i = s0 + tid; i < s1; i += 256) {
            unsigned e = colp[i];
            int ld = (int)(e & 127u);
            int pos = atomicAdd(&hist[ld], 1);
            colf[bse[ld] + pos] = (int)(e >> 7);
        }
        return;
    }

    // ---------------- gemm path ---------------------------------------------
    int l = tid & 63;                      // lane = row within block
    int w = __builtin_amdgcn_readfirstlane(tid >> 6);   // wave id (uniform)
    int w64 = tid & ~63;                   // wave base within block
    size_t rowbase = (size_t)(blockIdx.x - NB) * G1_ROWS;
    const float4* xg = (const float4*)x;
    float acc[16];
#pragma unroll
    for (int f = 0; f < 16; ++f) acc[f] = 0.f;

#define G1_DMA(DSTBASE, C)                                                    \
    {                                                                         \
        _Pragma("unroll")                                                     \
        for (int i = 0; i < 4; ++i) {                                         \
            int li = tid + i * 256;                                           \
            int r = li >> 4, kin = li & 15;                                   \
            int f4l = kin ^ (r & 15);                                         \
            size_t grow = rowbase + r;                                        \
            size_t g4 = (grow < (size_t)N_NODES)                              \
                        ? (grow * 128 + (C) * 16 + f4l)                       \
                        : (size_t)((C) * 16 + f4l);                           \
            const float4* srcp = xg + g4;                                     \
            float* dstf = (DSTBASE) + (size_t)(w64 + i * 256) * 4;            \
            __builtin_amdgcn_global_load_lds(                                 \
                (const __attribute__((address_space(1))) void*)srcp,          \
                (__attribute__((address_space(3))) void*)dstf, 16, 0, 0);     \
        }                                                                     \
    }

    G1_DMA(smemA, 0);                      // prologue: chunk 0 -> bufA
#pragma unroll 1
    for (int c = 0; c < 8; ++c) {
        asm volatile("s_waitcnt vmcnt(0)" ::: "memory");
        __syncthreads();                   // this chunk's tile is ready
        float* cur = (c & 1) ? smemB : smemA;
        float* nxt = (c & 1) ? smemA : smemB;
        if (c < 7) G1_DMA(nxt, c + 1);     // async: flies during compute
        const float* lbase = cur + l * 64;
#pragma unroll
        for (int kk = 0; kk < 4; ++kk) {
            int phys = (4 * w + kk) ^ (l & 15);
            f32x4 xv = *(const f32x4*)(lbase + phys * 4);
#pragma unroll
            for (int j = 0; j < 4; ++j) {
                const float* wr = W1 + (size_t)(c * 64 + 16 * w + 4 * kk + j) * HID;
#pragma unroll
                for (int f = 0; f < 16; ++f)
                    acc[f] = fmaf(xv[j], wr[f], acc[f]);
            }
        }
    }
#undef G1_DMA
    __syncthreads();                       // smemA reusable now

    // ---- combine 4-wave split-K partials via LDS [64][68]
    float* red = smemA;
#pragma unroll
    for (int f = 0; f < 16; ++f)
        red[l * 68 + w * 16 + f] = acc[f];
    __syncthreads();
    int r = tid >> 2;
    int fg = (tid & 3) * 4;
    size_t node = rowbase + r;
    if (node <= (size_t)N_NODES) {
        float o0 = 0.f, o1 = 0.f, o2 = 0.f, o3 = 0.f;
#pragma unroll
        for (int qq = 0; qq < 4; ++qq) {
            const float* rr = &red[r * 68 + qq * 16 + fg];
            o0 += rr[0]; o1 += rr[1]; o2 += rr[2]; o3 += rr[3];
        }
        float4 out = (node < (size_t)N_NODES)
                     ? make_float4(o0, o1, o2, o3)
                     : make_float4(0.f, 0.f, 0.f, 0.f);
        *(float4*)(xw + node * HID + fg) = out;
    }
}

// ---- layer-1 aggregation + FUSED layer-2: 16 lanes/node, NO atomics --------
__global__ __launch_bounds__(256)
void k_gather1(const int* __restrict__ noff, const int* __restrict__ ndeg,
               const int* __restrict__ colf, const float* __restrict__ dinv,
               const float* __restrict__ xw, const float* __restrict__ b1,
               const float* __restrict__ W2, float* __restrict__ h2s) {
    int t = blockIdx.x * 256 + threadIdx.x;   // grid exactly N_NODES*16
    int node = t >> 4;
    int l = t & 15;
    int start = noff[node];
    int end = start + ndeg[node];
    const f32x4* xw4 = (const f32x4*)xw;
    float acc[16];
#pragma unroll
    for (int r = 0; r < 16; ++r) acc[r] = 0.f;
    for (int j = start; j < end; j += 16) {
        int jl = j + l;
        int jj = min(jl, end - 1);
        int s = colf[jj];
        float ds = (jl < end) ? dinv[s] : 0.f;   // masked lanes contribute 0
        const f32x4* row = xw4 + (size_t)s * 4;
        f32x4 r0 = row[0], r1 = row[1], r2 = row[2], r3 = row[3];
        acc[0]  = fmaf(ds, r0.x, acc[0]);  acc[1]  = fmaf(ds, r0.y, acc[1]);
        acc[2]  = fmaf(ds, r0.z, acc[2]);  acc[3]  = fmaf(ds, r0.w, acc[3]);
        acc[4]  = fmaf(ds, r1.x, acc[4]);  acc[5]  = fmaf(ds, r1.y, acc[5]);
        acc[6]  = fmaf(ds, r1.z, acc[6]);  acc[7]  = fmaf(ds, r1.w, acc[7]);
        acc[8]  = fmaf(ds, r2.x, acc[8]);  acc[9]  = fmaf(ds, r2.y, acc[9]);
        acc[10] = fmaf(ds, r2.z, acc[10]); acc[11] = fmaf(ds, r2.w, acc[11]);
        acc[12] = fmaf(ds, r3.x, acc[12]); acc[13] = fmaf(ds, r3.y, acc[13]);
        acc[14] = fmaf(ds, r3.z, acc[14]); acc[15] = fmaf(ds, r3.w, acc[15]);
    }
    // butterfly transpose-reduce: lane l ends holding feature l
    float c8[8];
#pragma unroll
    for (int k = 0; k < 8; ++k) {
        float a0 = acc[2 * k], a1 = acc[2 * k + 1];
        float o0 = __shfl_xor(a0, 1, 16);
        float o1 = __shfl_xor(a1, 1, 16);
        c8[k] = (l & 1) ? (a1 + o1) : (a0 + o0);
    }
    float c4[4];
#pragma unroll
    for (int k = 0; k < 4; ++k) {
        float a0 = c8[2 * k], a1 = c8[2 * k + 1];
        float o0 = __shfl_xor(a0, 2, 16);
        float o1 = __shfl_xor(a1, 2, 16);
        c4[k] = (l & 2) ? (a1 + o1) : (a0 + o0);
    }
    float c2[2];
#pragma unroll
    for (int k = 0; k < 2; ++k) {
        float a0 = c4[2 * k], a1 = c4[2 * k + 1];
        float o0 = __shfl_xor(a0, 4, 16);
        float o1 = __shfl_xor(a1, 4, 16);
        c2[k] = (l & 4) ? (a1 + o1) : (a0 + o0);
    }
    float a0 = c2[0], a1 = c2[1];
    float o0 = __shfl_xor(a0, 8, 16);
    float o1 = __shfl_xor(a1, 8, 16);
    float tot = (l & 8) ? (a1 + o1) : (a0 + o0);

    float dd = dinv[node];
    float selfr = xw[(size_t)node * HID + l];          // raw xw
    float vv = fmaf(dd, tot + dd * selfr, b1[l]);      // b + dd*tot + dd^2*self
    float h = fmaxf(vv, 0.f);                          // relu(out1[node][l])

    // fused layer-2: h2s[node] = (out1row @ W2) * dd
    float2 w2 = ((const float2*)W2)[l];
    float g0 = h * w2.x, g1 = h * w2.y;
#pragma unroll
    for (int d = 1; d < 16; d <<= 1) {
        g0 += __shfl_xor(g0, d, 16);
        g1 += __shfl_xor(g1, d, 16);
    }
    if (l == 0)
        ((float2*)h2s)[node] = make_float2(g0 * dd, g1 * dd);
    if (t == 0)
        ((float2*)h2s)[N_NODES] = make_float2(0.f, 0.f);   // sentinel
}

// ---- layer-2 aggregation + log_softmax: 16 lanes/node ----------------------
__global__ __launch_bounds__(256)
void k_gather2(const int* __restrict__ noff, const int* __restrict__ ndeg,
               const int* __restrict__ colf, const float* __restrict__ dinv,
               const float* __restrict__ h2s, const float* __restrict__ b2,
               float* __restrict__ y) {
    int t = blockIdx.x * 256 + threadIdx.x;
    int node = t >> 4;
    int l = t & 15;
    int start = noff[node];
    int end = start + ndeg[node];
    const float2* h2v = (const float2*)h2s;
    float g0 = 0.f, g1 = 0.f;
    for (int j = start; j < end; j += 16) {
        int jl = j + l;
        int jj = min(jl, end - 1);
        int s = colf[jj];
        s = (jl < end) ? s : N_NODES;      // sentinel row = zeros
        float2 hv = h2v[s];
        g0 += hv.x; g1 += hv.y;
    }
#pragma unroll
    for (int d = 1; d < 16; d <<= 1) {
        g0 += __shfl_xor(g0, d, 16);
        g1 += __shfl_xor(g1, d, 16);
    }
    if (l == 0) {
        float2 self = h2v[node];
        float di = dinv[node];
        float v0 = fmaf(di, g0 + self.x, b2[0]);
        float v1 = fmaf(di, g1 + self.y, b2[1]);
        float m = fmaxf(v0, v1);
        float lse = m + logf(expf(v0 - m) + expf(v1 - m));
        ((float2*)y)[node] = make_float2(v0 - lse, v1 - lse);
    }
}

extern "C" void kernel_launch(void* const* d_in, const int* in_sizes, int n_in,
                              void* d_out, int out_size, void* d_ws, size_t ws_size,
                              hipStream_t stream) {
    const float* x  = (const float*)d_in[0];
    const void*  ei = d_in[1];
    const float* W1 = (const float*)d_in[2];
    const float* b1 = (const float*)d_in[3];
    const float* W2 = (const float*)d_in[4];
    const float* b2 = (const float*)d_in[5];
    float* y = (float*)d_out;

    char* w = (char*)d_ws;
    int*      gcnt = (int*)(w + 0);               // NB ints
    float*    dinv = (float*)(w + 4096);          // 400 KB
    int*      noff = (int*)(w + 413696);          // 400 KB
    int*      ndeg = (int*)(w + 823296);          // 400 KB
    unsigned* colp = (unsigned*)(w + 1232896);    // NB*BCAP*4 = 19.2 MB
    int*      colf = (int*)(w + 20451328);        // 19.2 MB
    float*    xw   = (float*)(w + 39669760);      // (N+1)*16 f32
    float*    h2s  = (float*)(w + 46069824);      // (N+1)*2 f32
    // total ws use: ~46.9 MB

    hipMemsetAsync(gcnt, 0, NB * sizeof(int), stream);
    k_sortscatter<<<NCHUNKS, 1024, 0, stream>>>(ei, gcnt, colp);
    k_csr_gemm<<<NB + G1_GRID, 256, 0, stream>>>(gcnt, colp, x, W1,
                                                 noff, ndeg, dinv, colf, xw);
    k_gather1<<<(N_NODES * 16) / 256, 256, 0, stream>>>(noff, ndeg, colf, dinv,
                                                        xw, b1, W2, h2s);
    k_gather2<<<(N_NODES * 16) / 256, 256, 0, stream>>>(noff, ndeg, colf, dinv,
                                                        h2s, b2, y);
}